// Round 1
// baseline (439.375 us; speedup 1.0000x reference)
//
#include <hip/hip_runtime.h>

#define TQ 4096  // table resolution over x in [0,12]

// ---------------- K0: build g(x) table: T[q][c] = b_a[c] + sum_j sin(x th_j) Wa[2j][c] + cos(x th_j) Wa[2j+1][c]
__global__ __launch_bounds__(256) void build_table(
    const float* __restrict__ W_a, const float* __restrict__ b_a,
    float* __restrict__ T) {
  __shared__ float sS[8][64], cS[8][64];
  int t = threadIdx.x;
  int row0 = blockIdx.x * 8;
  for (int i = t; i < 512; i += 256) {
    int r = i >> 6, j = i & 63;
    float x = (float)(row0 + r) * (12.0f / (float)(TQ - 1));
    float theta = expf(-(float)j * (9.210340371976184f / 64.0f));  // 10000^(-j/64)
    float om = x * theta;
    sS[r][j] = sinf(om);
    cS[r][j] = cosf(om);
  }
  __syncthreads();
  int c = t & 127, half = t >> 7;
  float b = b_a[c];
  float a0 = b, a1 = b, a2 = b, a3 = b;
  int r = half * 4;
  for (int j = 0; j < 64; ++j) {
    float ws = W_a[(2 * j) * 128 + c];
    float wc = W_a[(2 * j + 1) * 128 + c];
    a0 += sS[r + 0][j] * ws + cS[r + 0][j] * wc;
    a1 += sS[r + 1][j] * ws + cS[r + 1][j] * wc;
    a2 += sS[r + 2][j] * ws + cS[r + 2][j] * wc;
    a3 += sS[r + 3][j] * ws + cS[r + 3][j] * wc;
  }
  int rr = row0 + r;
  T[(size_t)(rr + 0) * 128 + c] = a0;
  T[(size_t)(rr + 1) * 128 + c] = a1;
  T[(size_t)(rr + 2) * 128 + c] = a2;
  T[(size_t)(rr + 3) * 128 + c] = a3;
}

// ---------------- K1: f = feats @ W_in + b_in   (N=40000 rows, 8 rows/block)
__global__ __launch_bounds__(256) void proj_in(
    const float* __restrict__ feats, const float* __restrict__ W_in,
    const float* __restrict__ b_in, float* __restrict__ f) {
  __shared__ float fS[8 * 64];
  int t = threadIdx.x;
  int row0 = blockIdx.x * 8;
  for (int i = t; i < 512; i += 256) fS[i] = feats[(size_t)row0 * 64 + i];
  __syncthreads();
  int c = t & 127, half = t >> 7;
  float bv = b_in[c];
  float acc[4] = {bv, bv, bv, bv};
  for (int i = 0; i < 64; ++i) {
    float w = W_in[i * 128 + c];
#pragma unroll
    for (int j = 0; j < 4; ++j) acc[j] += fS[(half * 4 + j) * 64 + i] * w;
  }
#pragma unroll
  for (int j = 0; j < 4; ++j)
    f[(size_t)(row0 + half * 4 + j) * 128 + c] = acc[j];
}

// ---------------- K2: qf/kf/vf = f @ W_{q,k,v} + b   (grid.y selects matrix)
__global__ __launch_bounds__(256) void proj_qkv(
    const float* __restrict__ f,
    const float* __restrict__ Wq, const float* __restrict__ bq,
    const float* __restrict__ Wk, const float* __restrict__ bk,
    const float* __restrict__ Wv, const float* __restrict__ bv,
    float* __restrict__ qf, float* __restrict__ kf, float* __restrict__ vf) {
  const float* W; const float* b; float* out;
  if (blockIdx.y == 0) { W = Wq; b = bq; out = qf; }
  else if (blockIdx.y == 1) { W = Wk; b = bk; out = kf; }
  else { W = Wv; b = bv; out = vf; }
  __shared__ float fS[8 * 128];
  int t = threadIdx.x;
  int row0 = blockIdx.x * 8;
  for (int i = t; i < 1024; i += 256) fS[i] = f[(size_t)row0 * 128 + i];
  __syncthreads();
  int c = t & 127, half = t >> 7;
  float b0 = b[c];
  float acc[4] = {b0, b0, b0, b0};
  for (int i = 0; i < 128; ++i) {
    float w = W[i * 128 + c];
#pragma unroll
    for (int j = 0; j < 4; ++j) acc[j] += fS[(half * 4 + j) * 128 + i] * w;
  }
#pragma unroll
  for (int j = 0; j < 4; ++j)
    out[(size_t)(row0 + half * 4 + j) * 128 + c] = acc[j];
}

// ---------------- K3: qp[m][h][c] = sum_d qf[node_idx[m]][h*32+d] * W_p[c][h*32+d]
__global__ __launch_bounds__(256) void compute_qp(
    const float* __restrict__ qf, const int* __restrict__ node_idx,
    const float* __restrict__ W_p, float* __restrict__ qp) {
  __shared__ float qS[8 * 128];
  int t = threadIdx.x;
  int m0 = blockIdx.x * 8;
#pragma unroll
  for (int i = 0; i < 4; ++i) {
    int idx = i * 256 + t;
    int mm = idx >> 7;
    int ni = node_idx[m0 + mm];
    qS[idx] = qf[(size_t)ni * 128 + (idx & 127)];
  }
  __syncthreads();
  int c = t & 127, half = t >> 7;
  float acc[4][4] = {};
  for (int h = 0; h < 4; ++h) {
#pragma unroll 8
    for (int d = 0; d < 32; ++d) {
      float wv = W_p[c * 128 + h * 32 + d];
#pragma unroll
      for (int mm = 0; mm < 4; ++mm)
        acc[mm][h] += qS[(half * 4 + mm) * 128 + h * 32 + d] * wv;
    }
  }
#pragma unroll
  for (int mm = 0; mm < 4; ++mm)
#pragma unroll
    for (int h = 0; h < 4; ++h)
      qp[((size_t)(m0 + half * 4 + mm) * 4 + h) * 128 + c] = acc[mm][h];
}

// ---------------- K4: fused attention, one wave per m (4 m per block)
__global__ __launch_bounds__(256) void attn_fused(
    const float* __restrict__ qf, const float* __restrict__ kf,
    const float* __restrict__ vf, const float* __restrict__ qp,
    const float* __restrict__ T, const float* __restrict__ ppfs,
    const int* __restrict__ node_idx, const int* __restrict__ group_idx,
    float* __restrict__ o_out) {
  __shared__ float posW[4][16][132];
  __shared__ float qpW[4][4][132];
  __shared__ float qW[4][128];
  __shared__ float attnW[4][64];
  __shared__ float ppfW[4][64];
  __shared__ int gW[4][16];

  int t = threadIdx.x;
  int w = t >> 6;
  int lane = t & 63;
  int m = blockIdx.x * 4 + w;

  // ---- stage per-m data ----
  ppfW[w][lane] = ppfs[(size_t)m * 64 + lane];
  if (lane < 16) gW[w][lane] = group_idx[m * 16 + lane];
  int ni = node_idx[m];
  qW[w][lane] = qf[(size_t)ni * 128 + lane];
  qW[w][lane + 64] = qf[(size_t)ni * 128 + 64 + lane];
#pragma unroll
  for (int i = 0; i < 8; ++i) {
    int idx = i * 64 + lane;
    qpW[w][idx >> 7][idx & 127] = qp[(size_t)m * 512 + idx];
  }
  __syncthreads();

  // ---- pos[k][c] = max_a lerp(T, x_{k,a})  (lane owns channels 2*lane, 2*lane+1)
  const float TS = (float)(TQ - 1) / 12.0f;
  int c0 = lane * 2;
#pragma unroll 4
  for (int k = 0; k < 16; ++k) {
    float p0 = -1e30f, p1 = -1e30f;
#pragma unroll
    for (int a = 0; a < 4; ++a) {
      float x = ppfW[w][k * 4 + a] * 3.8197186342054885f;  // FACTOR_A
      float u = x * TS;
      int i0 = (int)u;
      i0 = min(i0, TQ - 2);
      float fr = u - (float)i0;
      const float* Tp = T + (size_t)i0 * 128 + c0;
      float2 t0 = *(const float2*)Tp;
      float2 t1 = *(const float2*)(Tp + 128);
      p0 = fmaxf(p0, t0.x + fr * (t1.x - t0.x));
      p1 = fmaxf(p1, t0.y + fr * (t1.y - t0.y));
    }
    *(float2*)&posW[w][k][c0] = make_float2(p0, p1);
  }
  __syncthreads();

  // ---- scores + softmax: lane = h*16 + k
  {
    int h = lane >> 4, k = lane & 15;
    int g = gW[w][k];
    const float* krow = kf + (size_t)g * 128 + h * 32;
    const float* qrow = &qW[w][h * 32];
    float s = 0.f;
#pragma unroll
    for (int d4 = 0; d4 < 8; ++d4) {
      float4 kv = *(const float4*)(krow + d4 * 4);
      float4 qv = *(const float4*)(qrow + d4 * 4);
      s += qv.x * kv.x + qv.y * kv.y + qv.z * kv.z + qv.w * kv.w;
    }
#pragma unroll 8
    for (int c4 = 0; c4 < 32; ++c4) {
      float4 pv = *(const float4*)&posW[w][k][c4 * 4];
      float4 qpv = *(const float4*)&qpW[w][h][c4 * 4];
      s += pv.x * qpv.x + pv.y * qpv.y + pv.z * qpv.z + pv.w * qpv.w;
    }
    s *= 0.17677669529663687f;  // 1/sqrt(32); note: q.b_p term cancels in softmax
    float mx = s;
#pragma unroll
    for (int off = 1; off < 16; off <<= 1) mx = fmaxf(mx, __shfl_xor(mx, off));
    float e = __expf(s - mx);
    float sum = e;
#pragma unroll
    for (int off = 1; off < 16; off <<= 1) sum += __shfl_xor(sum, off);
    attnW[w][lane] = e / sum;
  }
  __syncthreads();

  // ---- o[c] = sum_k attn[h(c)][k] * vf[g_k][c]
  {
    float o0 = 0.f, o1 = 0.f;
    int h0 = lane >> 4;  // head of channels c0, c0+1
#pragma unroll
    for (int k = 0; k < 16; ++k) {
      float aw = attnW[w][h0 * 16 + k];
      float2 vv = *(const float2*)(vf + (size_t)gW[w][k] * 128 + c0);
      o0 += aw * vv.x;
      o1 += aw * vv.y;
    }
    *(float2*)&o_out[(size_t)m * 128 + c0] = make_float2(o0, o1);
  }
}

// ---------------- K5: hidden = o@W_o + b_o; res = f[node]+hidden; LN; out = normed@W_out + b_out
__global__ __launch_bounds__(256) void final_fused(
    const float* __restrict__ o, const float* __restrict__ f,
    const int* __restrict__ node_idx,
    const float* __restrict__ W_o, const float* __restrict__ b_o,
    const float* __restrict__ ln_g, const float* __restrict__ ln_b,
    const float* __restrict__ W_out, const float* __restrict__ b_out,
    float* __restrict__ out) {
  __shared__ float oS[16 * 128];
  __shared__ float rS[16 * 128];
  __shared__ float redS[16][2][2];
  int t = threadIdx.x;
  int m0 = blockIdx.x * 16;
  for (int i = t; i < 2048; i += 256) oS[i] = o[(size_t)m0 * 128 + i];
  __syncthreads();
  int c = t & 127, half = t >> 7;
  float acc[8];
  {
    float bv = b_o[c];
#pragma unroll
    for (int j = 0; j < 8; ++j) acc[j] = bv;
  }
  for (int i = 0; i < 128; ++i) {
    float wv = W_o[i * 128 + c];
#pragma unroll
    for (int j = 0; j < 8; ++j) acc[j] += oS[(half * 8 + j) * 128 + i] * wv;
  }
#pragma unroll
  for (int j = 0; j < 8; ++j) {
    int ni = node_idx[m0 + half * 8 + j];
    acc[j] += f[(size_t)ni * 128 + c];
  }
  int wih = (t >> 6) & 1;
#pragma unroll
  for (int j = 0; j < 8; ++j) {
    float s1 = acc[j], s2 = acc[j] * acc[j];
#pragma unroll
    for (int off = 1; off < 64; off <<= 1) {
      s1 += __shfl_xor(s1, off);
      s2 += __shfl_xor(s2, off);
    }
    if ((t & 63) == 0) {
      redS[half * 8 + j][wih][0] = s1;
      redS[half * 8 + j][wih][1] = s2;
    }
  }
  __syncthreads();
  float gv = ln_g[c], lb = ln_b[c];
#pragma unroll
  for (int j = 0; j < 8; ++j) {
    int row = half * 8 + j;
    float s1 = redS[row][0][0] + redS[row][1][0];
    float s2 = redS[row][0][1] + redS[row][1][1];
    float mean = s1 * (1.0f / 128.0f);
    float var = s2 * (1.0f / 128.0f) - mean * mean;
    float rstd = rsqrtf(var + 1e-5f);
    rS[row * 128 + c] = (acc[j] - mean) * rstd * gv + lb;
  }
  __syncthreads();
  float acc2[8];
  {
    float b2 = b_out[c];
#pragma unroll
    for (int j = 0; j < 8; ++j) acc2[j] = b2;
  }
  for (int i = 0; i < 128; ++i) {
    float wv = W_out[i * 128 + c];
#pragma unroll
    for (int j = 0; j < 8; ++j) acc2[j] += rS[(half * 8 + j) * 128 + i] * wv;
  }
#pragma unroll
  for (int j = 0; j < 8; ++j)
    out[(size_t)(m0 + half * 8 + j) * 128 + c] = acc2[j];
}

extern "C" void kernel_launch(void* const* d_in, const int* in_sizes, int n_in,
                              void* d_out, int out_size, void* d_ws, size_t ws_size,
                              hipStream_t stream) {
  const float* feats    = (const float*)d_in[0];
  const int*   node_idx = (const int*)d_in[1];
  const int*   group_idx= (const int*)d_in[2];
  const float* ppfs     = (const float*)d_in[3];
  const float* W_a      = (const float*)d_in[4];
  const float* b_a      = (const float*)d_in[5];
  const float* W_in     = (const float*)d_in[6];
  const float* b_in     = (const float*)d_in[7];
  const float* W_q      = (const float*)d_in[8];
  const float* b_q      = (const float*)d_in[9];
  const float* W_k      = (const float*)d_in[10];
  const float* b_k      = (const float*)d_in[11];
  const float* W_v      = (const float*)d_in[12];
  const float* b_v      = (const float*)d_in[13];
  const float* W_p      = (const float*)d_in[14];
  // b_p (d_in[15]) intentionally unused: its score contribution is constant
  // over k and cancels in the softmax.
  const float* W_o      = (const float*)d_in[16];
  const float* b_o      = (const float*)d_in[17];
  const float* ln_g     = (const float*)d_in[18];
  const float* ln_b     = (const float*)d_in[19];
  const float* W_out    = (const float*)d_in[20];
  const float* b_out    = (const float*)d_in[21];
  float* out = (float*)d_out;

  // workspace layout (floats): f, qf, kf, vf: 40000*128 each; qp: 20000*512;
  // T: 4096*128; o: 20000*128  => ~33.8M floats (135 MB)
  float* ws = (float*)d_ws;
  float* f  = ws;
  float* qf = ws + 5120000;
  float* kf = ws + 10240000;
  float* vf = ws + 15360000;
  float* qp = ws + 20480000;
  float* T  = ws + 30720000;
  float* o  = ws + 31244288;

  build_table<<<TQ / 8, 256, 0, stream>>>(W_a, b_a, T);
  proj_in<<<40000 / 8, 256, 0, stream>>>(feats, W_in, b_in, f);
  proj_qkv<<<dim3(40000 / 8, 3), 256, 0, stream>>>(f, W_q, b_q, W_k, b_k, W_v, b_v, qf, kf, vf);
  compute_qp<<<20000 / 8, 256, 0, stream>>>(qf, node_idx, W_p, qp);
  attn_fused<<<20000 / 4, 256, 0, stream>>>(qf, kf, vf, qp, T, ppfs, node_idx, group_idx, o);
  final_fused<<<20000 / 16, 256, 0, stream>>>(o, f, node_idx, W_o, b_o, ln_g, ln_b, W_out, b_out, out);
}

// Round 3
// 358.019 us; speedup vs baseline: 1.2272x; 1.2272x over previous
//
#include <hip/hip_runtime.h>

#define TQ 4096  // table resolution over x in [0,12]

__device__ __forceinline__ ushort f2bf(float x) {
  union { float f; unsigned u; } v; v.f = x;
  unsigned r = v.u + 0x7FFFu + ((v.u >> 16) & 1u);
  return (ushort)(r >> 16);
}
__device__ __forceinline__ float bf2f(ushort u) {
  union { unsigned u; float f; } v; v.u = ((unsigned)u) << 16;
  return v.f;
}

// ---------------- K0: build g(x) table: T[q][c] = b_a[c] + sum_j sin(x th_j) Wa[2j][c] + cos(x th_j) Wa[2j+1][c]
__global__ __launch_bounds__(256) void build_table(
    const float* __restrict__ W_a, const float* __restrict__ b_a,
    float* __restrict__ T) {
  __shared__ float sS[8][64], cS[8][64];
  int t = threadIdx.x;
  int row0 = blockIdx.x * 8;
  for (int i = t; i < 512; i += 256) {
    int r = i >> 6, j = i & 63;
    float x = (float)(row0 + r) * (12.0f / (float)(TQ - 1));
    float theta = expf(-(float)j * (9.210340371976184f / 64.0f));  // 10000^(-j/64)
    float om = x * theta;
    sS[r][j] = sinf(om);
    cS[r][j] = cosf(om);
  }
  __syncthreads();
  int c = t & 127, half = t >> 7;
  float b = b_a[c];
  float a0 = b, a1 = b, a2 = b, a3 = b;
  int r = half * 4;
  for (int j = 0; j < 64; ++j) {
    float ws = W_a[(2 * j) * 128 + c];
    float wc = W_a[(2 * j + 1) * 128 + c];
    a0 += sS[r + 0][j] * ws + cS[r + 0][j] * wc;
    a1 += sS[r + 1][j] * ws + cS[r + 1][j] * wc;
    a2 += sS[r + 2][j] * ws + cS[r + 2][j] * wc;
    a3 += sS[r + 3][j] * ws + cS[r + 3][j] * wc;
  }
  int rr = row0 + r;
  T[(size_t)(rr + 0) * 128 + c] = a0;
  T[(size_t)(rr + 1) * 128 + c] = a1;
  T[(size_t)(rr + 2) * 128 + c] = a2;
  T[(size_t)(rr + 3) * 128 + c] = a3;
}

// ---------------- W1: compose Wc{q,k,v} = W_in @ W_{q,k,v}; biases; copy W_in into Wbig[:,128:256]
// Wbig layout (64 x 768): [:,0:128]=Wcq  [:,128:256]=W_in  [:,256:768]=Wqp (filled by W2)
// Wkv  layout (64 x 256): [:,0:128]=Wck  [:,128:256]=Wcv
__global__ __launch_bounds__(256) void weight_prep1(
    const float* __restrict__ W_in, const float* __restrict__ b_in,
    const float* __restrict__ W_q, const float* __restrict__ b_q,
    const float* __restrict__ W_k, const float* __restrict__ b_k,
    const float* __restrict__ W_v, const float* __restrict__ b_v,
    float* __restrict__ Wkv, float* __restrict__ bkv,
    float* __restrict__ Wbig, float* __restrict__ bbig) {
  __shared__ float WinS[64 * 128];
  __shared__ float binS[128];
  int t = threadIdx.x;
  for (int i = t; i < 8192; i += 256) WinS[i] = W_in[i];
  if (t < 128) binS[t] = b_in[t];
  __syncthreads();
  const float* W; const float* b;
  int which = blockIdx.x;
  if (which == 0) { W = W_q; b = b_q; }
  else if (which == 1) { W = W_k; b = b_k; }
  else { W = W_v; b = b_v; }
  int c = t & 127, ih = t >> 7;  // ih selects rows ih*32 .. ih*32+31
  float acc[32] = {};
  float bacc = 0.f;
  for (int o = 0; o < 128; ++o) {
    float wv = W[o * 128 + c];
    bacc += binS[o] * wv;
#pragma unroll
    for (int j = 0; j < 32; ++j) acc[j] += WinS[(ih * 32 + j) * 128 + o] * wv;
  }
  bacc += b[c];
  if (which == 0) {
#pragma unroll
    for (int j = 0; j < 32; ++j) {
      int i = ih * 32 + j;
      Wbig[i * 768 + c] = acc[j];
      Wbig[i * 768 + 128 + c] = WinS[i * 128 + c];
    }
    if (ih == 0) { bbig[c] = bacc; bbig[128 + c] = binS[c]; }
  } else if (which == 1) {
#pragma unroll
    for (int j = 0; j < 32; ++j) Wkv[(ih * 32 + j) * 256 + c] = acc[j];
    if (ih == 0) bkv[c] = bacc;
  } else {
#pragma unroll
    for (int j = 0; j < 32; ++j) Wkv[(ih * 32 + j) * 256 + 128 + c] = acc[j];
    if (ih == 0) bkv[128 + c] = bacc;
  }
}

// ---------------- W2: Wqp[i][h*128+c] = sum_d Wcq[i][h*32+d] * W_p[c][h*32+d]  -> Wbig[:,256:768]
__global__ __launch_bounds__(256) void weight_prep2(
    const float* __restrict__ W_p, float* Wbig, float* bbig) {
  __shared__ float WcqS[64][33];
  __shared__ float bcqS[32];
  int t = threadIdx.x;
  int blk = blockIdx.x;     // 8 blocks, each 64 hc-columns
  int h = blk >> 1;
  for (int idx = t; idx < 2048; idx += 256) {
    int i = idx >> 5, d = idx & 31;
    WcqS[i][d] = Wbig[i * 768 + h * 32 + d];
  }
  if (t < 32) bcqS[t] = bbig[h * 32 + t];
  __syncthreads();
  int hc = blk * 64 + (t & 63);  // global col in [0,512)
  int c = hc & 127;
  int rg = t >> 6;               // 4 row-groups x 16 rows
  float acc[16] = {};
  float bacc = 0.f;
  for (int d = 0; d < 32; ++d) {
    float wp = W_p[c * 128 + h * 32 + d];
    bacc += bcqS[d] * wp;
#pragma unroll
    for (int j = 0; j < 16; ++j) acc[j] += WcqS[rg * 16 + j][d] * wp;
  }
#pragma unroll
  for (int j = 0; j < 16; ++j) Wbig[(rg * 16 + j) * 768 + 256 + hc] = acc[j];
  if (rg == 0) bbig[256 + hc] = bacc;
}

// ---------------- K_kv: kv[n][0:128]=k, [128:256]=v ; = feats @ Wkv + bkv  (K=64)
__global__ __launch_bounds__(256) void proj_kv(
    const float* __restrict__ feats, const float* __restrict__ Wkv,
    const float* __restrict__ bkv, float* __restrict__ kv) {
  __shared__ float fTS[64][20];  // transposed: [i][r], 16 rows
  int t = threadIdx.x;
  int row0 = blockIdx.x * 16;
#pragma unroll
  for (int ii = 0; ii < 4; ++ii) {
    int idx = ii * 256 + t;
    int r = idx >> 6, i = idx & 63;
    fTS[i][r] = feats[(size_t)(row0 + r) * 64 + i];
  }
  __syncthreads();
  int c = t;
  float bv = bkv[c];
  float acc[16];
#pragma unroll
  for (int j = 0; j < 16; ++j) acc[j] = bv;
  for (int i = 0; i < 64; ++i) {
    float w = Wkv[i * 256 + c];
    float fv[16];
    *(float4*)&fv[0]  = *(const float4*)&fTS[i][0];
    *(float4*)&fv[4]  = *(const float4*)&fTS[i][4];
    *(float4*)&fv[8]  = *(const float4*)&fTS[i][8];
    *(float4*)&fv[12] = *(const float4*)&fTS[i][12];
#pragma unroll
    for (int j = 0; j < 16; ++j) acc[j] += fv[j] * w;
  }
#pragma unroll
  for (int j = 0; j < 16; ++j) kv[(size_t)(row0 + j) * 256 + c] = acc[j];
}

// ---------------- K_m: mrow[m][0:128]=qrow, [128:256]=fres, [256:768]=qp
// = feats[node_idx[m]] @ Wbig + bbig  (K=64)
__global__ __launch_bounds__(256) void proj_m(
    const float* __restrict__ feats, const int* __restrict__ node_idx,
    const float* __restrict__ Wbig, const float* __restrict__ bbig,
    float* __restrict__ mrow) {
  __shared__ float fTS[64][12];  // [i][r], 8 rows
  int t = threadIdx.x;
  int m0 = blockIdx.x * 8;
#pragma unroll
  for (int ii = 0; ii < 2; ++ii) {
    int idx = ii * 256 + t;
    int r = idx >> 6, i = idx & 63;
    int ni = node_idx[m0 + r];
    fTS[i][r] = feats[(size_t)ni * 64 + i];
  }
  __syncthreads();
  int c = t;  // 0..255; columns {c, 256+c, 512+c}
  float a0[8], a1[8], a2[8];
  float b0 = bbig[c], b1 = bbig[256 + c], b2 = bbig[512 + c];
#pragma unroll
  for (int j = 0; j < 8; ++j) { a0[j] = b0; a1[j] = b1; a2[j] = b2; }
  for (int i = 0; i < 64; ++i) {
    float w0 = Wbig[i * 768 + c];
    float w1 = Wbig[i * 768 + 256 + c];
    float w2 = Wbig[i * 768 + 512 + c];
    float fv[8];
    *(float4*)&fv[0] = *(const float4*)&fTS[i][0];
    *(float4*)&fv[4] = *(const float4*)&fTS[i][4];
#pragma unroll
    for (int j = 0; j < 8; ++j) {
      a0[j] += fv[j] * w0; a1[j] += fv[j] * w1; a2[j] += fv[j] * w2;
    }
  }
#pragma unroll
  for (int j = 0; j < 8; ++j) {
    size_t base = (size_t)(m0 + j) * 768;
    mrow[base + c] = a0[j];
    mrow[base + 256 + c] = a1[j];
    mrow[base + 512 + c] = a2[j];
  }
}

// ---------------- K4: fused attention, one wave per m (4 m per block)
__global__ __launch_bounds__(256) void attn_fused(
    const float* __restrict__ kv, const float* __restrict__ mrow,
    const float* __restrict__ T, const float* __restrict__ ppfs,
    const int* __restrict__ group_idx, float* __restrict__ o_out) {
  __shared__ ushort posW[4][16][136];   // bf16 pos
  __shared__ float qpW[4][4][132];
  __shared__ float qW[4][4][36];        // per-head q, padded
  __shared__ float attnW[4][64];
  __shared__ float ppfW[4][64];
  __shared__ int gW[4][16];

  int t = threadIdx.x;
  int w = t >> 6;
  int lane = t & 63;
  int m = blockIdx.x * 4 + w;
  const float* mr = mrow + (size_t)m * 768;

  // ---- stage per-m data ----
  ppfW[w][lane] = ppfs[(size_t)m * 64 + lane];
  if (lane < 16) gW[w][lane] = group_idx[m * 16 + lane];
  {
    float q0 = mr[lane];
    float q1 = mr[64 + lane];
    qW[w][lane >> 5][lane & 31] = q0;
    int c1 = 64 + lane;
    qW[w][c1 >> 5][c1 & 31] = q1;
  }
#pragma unroll
  for (int i = 0; i < 8; ++i) {
    int idx = i * 64 + lane;
    qpW[w][idx >> 7][idx & 127] = mr[256 + idx];
  }
  __syncthreads();

  // ---- pos[k][c] = max_a lerp(T, x_{k,a})  (lane owns channels 2*lane, 2*lane+1)
  const float TS = (float)(TQ - 1) / 12.0f;
  int c0 = lane * 2;
#pragma unroll 4
  for (int k = 0; k < 16; ++k) {
    float p0 = -1e30f, p1 = -1e30f;
#pragma unroll
    for (int a = 0; a < 4; ++a) {
      float x = ppfW[w][k * 4 + a] * 3.8197186342054885f;  // FACTOR_A
      float u = x * TS;
      int i0 = (int)u;
      i0 = min(i0, TQ - 2);
      float fr = u - (float)i0;
      const float* Tp = T + (size_t)i0 * 128 + c0;
      float2 t0 = *(const float2*)Tp;
      float2 t1 = *(const float2*)(Tp + 128);
      p0 = fmaxf(p0, t0.x + fr * (t1.x - t0.x));
      p1 = fmaxf(p1, t0.y + fr * (t1.y - t0.y));
    }
    *(ushort2*)&posW[w][k][c0] = make_ushort2(f2bf(p0), f2bf(p1));
  }
  __syncthreads();

  // ---- scores + softmax: lane = h*16 + k
  {
    int h = lane >> 4, k = lane & 15;
    int g = gW[w][k];
    const float* krow = kv + (size_t)g * 256 + h * 32;
    float s = 0.f;
#pragma unroll
    for (int d4 = 0; d4 < 8; ++d4) {
      float4 kvv = *(const float4*)(krow + d4 * 4);
      float4 qv = *(const float4*)&qW[w][h][d4 * 4];
      s += qv.x * kvv.x + qv.y * kvv.y + qv.z * kvv.z + qv.w * kvv.w;
    }
#pragma unroll 8
    for (int c4 = 0; c4 < 32; ++c4) {
      ushort4 pu = *(const ushort4*)&posW[w][k][c4 * 4];
      float4 qpv = *(const float4*)&qpW[w][h][c4 * 4];
      s += bf2f(pu.x) * qpv.x + bf2f(pu.y) * qpv.y +
           bf2f(pu.z) * qpv.z + bf2f(pu.w) * qpv.w;
    }
    s *= 0.17677669529663687f;  // 1/sqrt(32); q.b_p term cancels in softmax
    float mx = s;
#pragma unroll
    for (int off = 1; off < 16; off <<= 1) mx = fmaxf(mx, __shfl_xor(mx, off));
    float e = __expf(s - mx);
    float sum = e;
#pragma unroll
    for (int off = 1; off < 16; off <<= 1) sum += __shfl_xor(sum, off);
    attnW[w][lane] = e / sum;
  }
  __syncthreads();

  // ---- o[c] = sum_k attn[h(c)][k] * v[g_k][c]
  {
    float o0 = 0.f, o1 = 0.f;
    int h0 = lane >> 4;  // head of channels c0, c0+1
#pragma unroll
    for (int k = 0; k < 16; ++k) {
      float aw = attnW[w][h0 * 16 + k];
      float2 vv = *(const float2*)(kv + (size_t)gW[w][k] * 256 + 128 + c0);
      o0 += aw * vv.x;
      o1 += aw * vv.y;
    }
    *(float2*)&o_out[(size_t)m * 128 + c0] = make_float2(o0, o1);
  }
}

// ---------------- K5: hidden = o@W_o + b_o; res = fres + hidden; LN; out = normed@W_out + b_out
__global__ __launch_bounds__(256) void final_fused(
    const float* __restrict__ o, const float* __restrict__ mrow,
    const float* __restrict__ W_o, const float* __restrict__ b_o,
    const float* __restrict__ ln_g, const float* __restrict__ ln_b,
    const float* __restrict__ W_out, const float* __restrict__ b_out,
    float* __restrict__ out) {
  __shared__ float oS[16 * 128];
  __shared__ float rS[16 * 128];
  __shared__ float redS[16][2][2];
  int t = threadIdx.x;
  int m0 = blockIdx.x * 16;
  for (int i = t; i < 2048; i += 256) oS[i] = o[(size_t)m0 * 128 + i];
  __syncthreads();
  int c = t & 127, half = t >> 7;
  float acc[8];
  {
    float bv = b_o[c];
#pragma unroll
    for (int j = 0; j < 8; ++j) acc[j] = bv;
  }
  for (int i = 0; i < 128; ++i) {
    float wv = W_o[i * 128 + c];
#pragma unroll
    for (int j = 0; j < 8; ++j) acc[j] += oS[(half * 8 + j) * 128 + i] * wv;
  }
#pragma unroll
  for (int j = 0; j < 8; ++j)
    acc[j] += mrow[(size_t)(m0 + half * 8 + j) * 768 + 128 + c];
  int wih = (t >> 6) & 1;
#pragma unroll
  for (int j = 0; j < 8; ++j) {
    float s1 = acc[j], s2 = acc[j] * acc[j];
#pragma unroll
    for (int off = 1; off < 64; off <<= 1) {
      s1 += __shfl_xor(s1, off);
      s2 += __shfl_xor(s2, off);
    }
    if ((t & 63) == 0) {
      redS[half * 8 + j][wih][0] = s1;
      redS[half * 8 + j][wih][1] = s2;
    }
  }
  __syncthreads();
  float gv = ln_g[c], lb = ln_b[c];
#pragma unroll
  for (int j = 0; j < 8; ++j) {
    int row = half * 8 + j;
    float s1 = redS[row][0][0] + redS[row][1][0];
    float s2 = redS[row][0][1] + redS[row][1][1];
    float mean = s1 * (1.0f / 128.0f);
    float var = s2 * (1.0f / 128.0f) - mean * mean;
    float rstd = rsqrtf(var + 1e-5f);
    rS[row * 128 + c] = (acc[j] - mean) * rstd * gv + lb;
  }
  __syncthreads();
  float acc2[8];
  {
    float b2 = b_out[c];
#pragma unroll
    for (int j = 0; j < 8; ++j) acc2[j] = b2;
  }
  for (int i = 0; i < 128; ++i) {
    float wv = W_out[i * 128 + c];
#pragma unroll
    for (int j = 0; j < 8; ++j) acc2[j] += rS[(half * 8 + j) * 128 + i] * wv;
  }
#pragma unroll
  for (int j = 0; j < 8; ++j)
    out[(size_t)(m0 + half * 8 + j) * 128 + c] = acc2[j];
}

extern "C" void kernel_launch(void* const* d_in, const int* in_sizes, int n_in,
                              void* d_out, int out_size, void* d_ws, size_t ws_size,
                              hipStream_t stream) {
  const float* feats    = (const float*)d_in[0];
  const int*   node_idx = (const int*)d_in[1];
  const int*   group_idx= (const int*)d_in[2];
  const float* ppfs     = (const float*)d_in[3];
  const float* W_a      = (const float*)d_in[4];
  const float* b_a      = (const float*)d_in[5];
  const float* W_in     = (const float*)d_in[6];
  const float* b_in     = (const float*)d_in[7];
  const float* W_q      = (const float*)d_in[8];
  const float* b_q      = (const float*)d_in[9];
  const float* W_k      = (const float*)d_in[10];
  const float* b_k      = (const float*)d_in[11];
  const float* W_v      = (const float*)d_in[12];
  const float* b_v      = (const float*)d_in[13];
  const float* W_p      = (const float*)d_in[14];
  // b_p (d_in[15]) unused: its score contribution is constant over k -> cancels in softmax.
  const float* W_o      = (const float*)d_in[16];
  const float* b_o      = (const float*)d_in[17];
  const float* ln_g     = (const float*)d_in[18];
  const float* ln_b     = (const float*)d_in[19];
  const float* W_out    = (const float*)d_in[20];
  const float* b_out    = (const float*)d_in[21];
  float* out = (float*)d_out;

  // ws layout (floats)
  float* ws   = (float*)d_ws;
  float* kv   = ws;                       // 40000*256 = 10,240,000
  float* mrow = ws + 10240000;            // 20000*768 = 15,360,000
  float* T    = ws + 25600000;            // 4096*128  = 524,288
  float* o    = ws + 26124288;            // 20000*128 = 2,560,000
  float* Wkv  = ws + 28684288;            // 64*256
  float* bkv  = ws + 28700672;            // 256
  float* Wbig = ws + 28700928;            // 64*768
  float* bbig = ws + 28750080;            // 768

  build_table<<<TQ / 8, 256, 0, stream>>>(W_a, b_a, T);
  weight_prep1<<<3, 256, 0, stream>>>(W_in, b_in, W_q, b_q, W_k, b_k, W_v, b_v,
                                      Wkv, bkv, Wbig, bbig);
  weight_prep2<<<8, 256, 0, stream>>>(W_p, Wbig, bbig);
  proj_kv<<<40000 / 16, 256, 0, stream>>>(feats, Wkv, bkv, kv);
  proj_m<<<20000 / 8, 256, 0, stream>>>(feats, node_idx, Wbig, bbig, mrow);
  attn_fused<<<20000 / 4, 256, 0, stream>>>(kv, mrow, T, ppfs, group_idx, o);
  final_fused<<<20000 / 16, 256, 0, stream>>>(o, mrow, W_o, b_o, ln_g, ln_b,
                                              W_out, b_out, out);
}

// Round 6
// 331.608 us; speedup vs baseline: 1.3250x; 1.0796x over previous
//
#include <hip/hip_runtime.h>

#define TQ 4096  // table resolution over x in [0,12]

__device__ __forceinline__ ushort f2bf(float x) {
  union { float f; unsigned u; } v; v.f = x;
  unsigned r = v.u + 0x7FFFu + ((v.u >> 16) & 1u);
  return (ushort)(r >> 16);
}
__device__ __forceinline__ float bflo(unsigned u) {
  union { unsigned u; float f; } v; v.u = u << 16;
  return v.f;
}
__device__ __forceinline__ float bfhi(unsigned u) {
  union { unsigned u; float f; } v; v.u = u & 0xffff0000u;
  return v.f;
}

// ---------------- W1: compose Wc{q,k,v} = W_in @ W_{q,k,v}; biases; copy W_in into Wbig[:,128:256]
// Wbig layout (64 x 768): [:,0:128]=Wcq  [:,128:256]=W_in  [:,256:768]=Wqp (filled by W2)
// Wkv  layout (64 x 256): [:,0:128]=Wck  [:,128:256]=Wcv
__global__ __launch_bounds__(256) void weight_prep1(
    const float* __restrict__ W_in, const float* __restrict__ b_in,
    const float* __restrict__ W_q, const float* __restrict__ b_q,
    const float* __restrict__ W_k, const float* __restrict__ b_k,
    const float* __restrict__ W_v, const float* __restrict__ b_v,
    float* __restrict__ Wkv, float* __restrict__ bkv,
    float* __restrict__ Wbig, float* __restrict__ bbig) {
  __shared__ float WinS[64 * 128];
  __shared__ float binS[128];
  int t = threadIdx.x;
  for (int i = t; i < 8192; i += 256) WinS[i] = W_in[i];
  if (t < 128) binS[t] = b_in[t];
  __syncthreads();
  const float* W; const float* b;
  int which = blockIdx.x;
  if (which == 0) { W = W_q; b = b_q; }
  else if (which == 1) { W = W_k; b = b_k; }
  else { W = W_v; b = b_v; }
  int c = t & 127, ih = t >> 7;  // ih selects rows ih*32 .. ih*32+31
  float acc[32] = {};
  float bacc = 0.f;
  for (int o = 0; o < 128; ++o) {
    float wv = W[o * 128 + c];
    bacc += binS[o] * wv;
#pragma unroll
    for (int j = 0; j < 32; ++j) acc[j] += WinS[(ih * 32 + j) * 128 + o] * wv;
  }
  bacc += b[c];
  if (which == 0) {
#pragma unroll
    for (int j = 0; j < 32; ++j) {
      int i = ih * 32 + j;
      Wbig[i * 768 + c] = acc[j];
      Wbig[i * 768 + 128 + c] = WinS[i * 128 + c];
    }
    if (ih == 0) { bbig[c] = bacc; bbig[128 + c] = binS[c]; }
  } else if (which == 1) {
#pragma unroll
    for (int j = 0; j < 32; ++j) Wkv[(ih * 32 + j) * 256 + c] = acc[j];
    if (ih == 0) bkv[c] = bacc;
  } else {
#pragma unroll
    for (int j = 0; j < 32; ++j) Wkv[(ih * 32 + j) * 256 + 128 + c] = acc[j];
    if (ih == 0) bkv[128 + c] = bacc;
  }
}

// ---------------- W2: Wqp[i][h*128+c] = sum_d Wcq[i][h*32+d] * W_p[c][h*32+d]  -> Wbig[:,256:768]
__global__ __launch_bounds__(256) void weight_prep2(
    const float* __restrict__ W_p, float* Wbig, float* bbig) {
  __shared__ float WcqS[64][33];
  __shared__ float bcqS[32];
  int t = threadIdx.x;
  int blk = blockIdx.x;     // 8 blocks, each 64 hc-columns
  int h = blk >> 1;
  for (int idx = t; idx < 2048; idx += 256) {
    int i = idx >> 5, d = idx & 31;
    WcqS[i][d] = Wbig[i * 768 + h * 32 + d];
  }
  if (t < 32) bcqS[t] = bbig[h * 32 + t];
  __syncthreads();
  int hc = blk * 64 + (t & 63);  // global col in [0,512)
  int c = hc & 127;
  int rg = t >> 6;               // 4 row-groups x 16 rows
  float acc[16] = {};
  float bacc = 0.f;
  for (int d = 0; d < 32; ++d) {
    float wp = W_p[c * 128 + h * 32 + d];
    bacc += bcqS[d] * wp;
#pragma unroll
    for (int j = 0; j < 16; ++j) acc[j] += WcqS[rg * 16 + j][d] * wp;
  }
#pragma unroll
  for (int j = 0; j < 16; ++j) Wbig[(rg * 16 + j) * 768 + 256 + hc] = acc[j];
  if (rg == 0) bbig[256 + hc] = bacc;
}

// ---------------- mega_proj: blocks [0,2500) proj_kv ; [2500,5000) proj_m ; [5000,5512) build_table
// proj_kv:     kvb[n][256] (bf16) = feats @ Wkv + bkv
// proj_m:      mrow[m][0:128]=q, [128:256]=fres (f32);  qpb[m][512] (bf16)
// build_table: T[q][c] (f32)
__global__ __launch_bounds__(256) void mega_proj(
    const float* __restrict__ feats, const int* __restrict__ node_idx,
    const float* __restrict__ Wkv, const float* __restrict__ bkv,
    const float* __restrict__ Wbig, const float* __restrict__ bbig,
    const float* __restrict__ W_a, const float* __restrict__ b_a,
    ushort* __restrict__ kvb, float* __restrict__ mrow,
    ushort* __restrict__ qpb, float* __restrict__ T) {
  __shared__ float smem[64 * 20];
  int t = threadIdx.x;
  int b = blockIdx.x;
  if (b < 2500) {
    // ---- proj_kv: 16 rows
    float (*fTS)[20] = (float(*)[20])smem;
    int row0 = b * 16;
#pragma unroll
    for (int ii = 0; ii < 4; ++ii) {
      int idx = ii * 256 + t;
      int r = idx >> 6, i = idx & 63;
      fTS[i][r] = feats[(size_t)(row0 + r) * 64 + i];
    }
    __syncthreads();
    int c = t;
    float bv = bkv[c];
    float acc[16];
#pragma unroll
    for (int j = 0; j < 16; ++j) acc[j] = bv;
    for (int i = 0; i < 64; ++i) {
      float w = Wkv[i * 256 + c];
      float fv[16];
      *(float4*)&fv[0]  = *(const float4*)&fTS[i][0];
      *(float4*)&fv[4]  = *(const float4*)&fTS[i][4];
      *(float4*)&fv[8]  = *(const float4*)&fTS[i][8];
      *(float4*)&fv[12] = *(const float4*)&fTS[i][12];
#pragma unroll
      for (int j = 0; j < 16; ++j) acc[j] += fv[j] * w;
    }
#pragma unroll
    for (int j = 0; j < 16; ++j)
      kvb[(size_t)(row0 + j) * 256 + c] = f2bf(acc[j]);
  } else if (b < 5000) {
    // ---- proj_m: 8 m-rows
    float (*fTS)[12] = (float(*)[12])smem;
    int m0 = (b - 2500) * 8;
#pragma unroll
    for (int ii = 0; ii < 2; ++ii) {
      int idx = ii * 256 + t;
      int r = idx >> 6, i = idx & 63;
      int ni = node_idx[m0 + r];
      fTS[i][r] = feats[(size_t)ni * 64 + i];
    }
    __syncthreads();
    int c = t;  // composed cols {c, 256+c, 512+c} of Wbig
    float a0[8], a1[8], a2[8];
    float b0 = bbig[c], b1 = bbig[256 + c], b2 = bbig[512 + c];
#pragma unroll
    for (int j = 0; j < 8; ++j) { a0[j] = b0; a1[j] = b1; a2[j] = b2; }
    for (int i = 0; i < 64; ++i) {
      float w0 = Wbig[i * 768 + c];
      float w1 = Wbig[i * 768 + 256 + c];
      float w2 = Wbig[i * 768 + 512 + c];
      float fv[8];
      *(float4*)&fv[0] = *(const float4*)&fTS[i][0];
      *(float4*)&fv[4] = *(const float4*)&fTS[i][4];
#pragma unroll
      for (int j = 0; j < 8; ++j) {
        a0[j] += fv[j] * w0; a1[j] += fv[j] * w1; a2[j] += fv[j] * w2;
      }
    }
#pragma unroll
    for (int j = 0; j < 8; ++j) {
      int m = m0 + j;
      mrow[(size_t)m * 256 + c] = a0[j];            // q (c<128) | fres (c>=128)
      qpb[(size_t)m * 512 + c] = f2bf(a1[j]);       // qp col c
      qpb[(size_t)m * 512 + 256 + c] = f2bf(a2[j]); // qp col 256+c
    }
  } else {
    // ---- build_table: 8 table rows
    float (*sS)[64] = (float(*)[64])smem;
    float (*cS)[64] = (float(*)[64])(smem + 512);
    int row0 = (b - 5000) * 8;
    for (int i = t; i < 512; i += 256) {
      int r = i >> 6, j = i & 63;
      float x = (float)(row0 + r) * (12.0f / (float)(TQ - 1));
      float theta = expf(-(float)j * (9.210340371976184f / 64.0f));  // 10000^(-j/64)
      float om = x * theta;
      sS[r][j] = sinf(om);
      cS[r][j] = cosf(om);
    }
    __syncthreads();
    int c = t & 127, half = t >> 7;
    float bb = b_a[c];
    float a0 = bb, a1 = bb, a2 = bb, a3 = bb;
    int r = half * 4;
    for (int j = 0; j < 64; ++j) {
      float ws = W_a[(2 * j) * 128 + c];
      float wc = W_a[(2 * j + 1) * 128 + c];
      a0 += sS[r + 0][j] * ws + cS[r + 0][j] * wc;
      a1 += sS[r + 1][j] * ws + cS[r + 1][j] * wc;
      a2 += sS[r + 2][j] * ws + cS[r + 2][j] * wc;
      a3 += sS[r + 3][j] * ws + cS[r + 3][j] * wc;
    }
    int rr = row0 + r;
    T[(size_t)(rr + 0) * 128 + c] = a0;
    T[(size_t)(rr + 1) * 128 + c] = a1;
    T[(size_t)(rr + 2) * 128 + c] = a2;
    T[(size_t)(rr + 3) * 128 + c] = a3;
  }
}

// ---------------- attn: one wave per m (4 m per block); bf16 kv/qp/pos
__global__ __launch_bounds__(256) void attn_fused(
    const ushort* __restrict__ kvb, const float* __restrict__ mrow,
    const ushort* __restrict__ qpb, const float* __restrict__ T,
    const float* __restrict__ ppfs, const int* __restrict__ group_idx,
    float* __restrict__ o_out) {
  __shared__ unsigned posW[4][16][68];  // packed bf16x2, channel pair per uint
  __shared__ unsigned qpW[4][4][68];    // packed bf16x2
  __shared__ float qW[4][4][36];        // per-head q (f32)
  __shared__ float attnW[4][64];
  __shared__ float ppfW[4][64];
  __shared__ int gW[4][16];

  int t = threadIdx.x;
  int w = t >> 6;
  int lane = t & 63;
  int m = blockIdx.x * 4 + w;

  // ---- stage per-m data ----
  ppfW[w][lane] = ppfs[(size_t)m * 64 + lane];
  if (lane < 16) gW[w][lane] = group_idx[m * 16 + lane];
  const float* mr = mrow + (size_t)m * 256;
  {
    float q0 = mr[lane];
    float q1 = mr[64 + lane];
    qW[w][lane >> 5][lane & 31] = q0;
    int c1 = 64 + lane;
    qW[w][c1 >> 5][c1 & 31] = q1;
  }
  {
    uint4 qpu = ((const uint4*)(qpb + (size_t)m * 512))[lane];
    int j = lane * 4;         // uint index within row (0..255)
    int h = j >> 6, j2 = j & 63;
    qpW[w][h][j2 + 0] = qpu.x;
    qpW[w][h][j2 + 1] = qpu.y;
    qpW[w][h][j2 + 2] = qpu.z;
    qpW[w][h][j2 + 3] = qpu.w;
  }
  __syncthreads();

  // ---- pos[k][c] = max_a lerp(T, x_{k,a})  (lane owns channel pair 2*lane, 2*lane+1)
  const float TS = (float)(TQ - 1) / 12.0f;
  int c0 = lane * 2;
#pragma unroll 4
  for (int k = 0; k < 16; ++k) {
    float p0 = -1e30f, p1 = -1e30f;
#pragma unroll
    for (int a = 0; a < 4; ++a) {
      float x = ppfW[w][k * 4 + a] * 3.8197186342054885f;  // FACTOR_A
      float u = x * TS;
      int i0 = (int)u;
      i0 = min(i0, TQ - 2);
      float fr = u - (float)i0;
      const float* Tp = T + (size_t)i0 * 128 + c0;
      float2 t0 = *(const float2*)Tp;
      float2 t1 = *(const float2*)(Tp + 128);
      p0 = fmaxf(p0, t0.x + fr * (t1.x - t0.x));
      p1 = fmaxf(p1, t0.y + fr * (t1.y - t0.y));
    }
    posW[w][k][lane] = (unsigned)f2bf(p0) | ((unsigned)f2bf(p1) << 16);
  }
  __syncthreads();

  // ---- scores + softmax: lane = h*16 + k
  {
    int h = lane >> 4, k = lane & 15;
    int g = gW[w][k];
    const uint4* kp = (const uint4*)(kvb + (size_t)g * 256 + h * 32);  // 16B aligned
    float s = 0.f;
#pragma unroll
    for (int d8 = 0; d8 < 4; ++d8) {
      uint4 kk = kp[d8];
      float4 qv0 = *(const float4*)&qW[w][h][d8 * 8];
      float4 qv1 = *(const float4*)&qW[w][h][d8 * 8 + 4];
      s += qv0.x * bflo(kk.x) + qv0.y * bfhi(kk.x) +
           qv0.z * bflo(kk.y) + qv0.w * bfhi(kk.y) +
           qv1.x * bflo(kk.z) + qv1.y * bfhi(kk.z) +
           qv1.z * bflo(kk.w) + qv1.w * bfhi(kk.w);
    }
#pragma unroll 8
    for (int c4 = 0; c4 < 32; ++c4) {
      unsigned pu0 = posW[w][k][2 * c4], pu1 = posW[w][k][2 * c4 + 1];
      unsigned qu0 = qpW[w][h][2 * c4], qu1 = qpW[w][h][2 * c4 + 1];
      s += bflo(pu0) * bflo(qu0) + bfhi(pu0) * bfhi(qu0) +
           bflo(pu1) * bflo(qu1) + bfhi(pu1) * bfhi(qu1);
    }
    s *= 0.17677669529663687f;  // 1/sqrt(32); q.b_p term cancels in softmax
    float mx = s;
#pragma unroll
    for (int off = 1; off < 16; off <<= 1) mx = fmaxf(mx, __shfl_xor(mx, off));
    float e = __expf(s - mx);
    float sum = e;
#pragma unroll
    for (int off = 1; off < 16; off <<= 1) sum += __shfl_xor(sum, off);
    attnW[w][lane] = e / sum;
  }
  __syncthreads();

  // ---- o[c] = sum_k attn[h(c)][k] * v[g_k][c]
  {
    float o0 = 0.f, o1 = 0.f;
    int h0 = lane >> 4;  // head of channels c0, c0+1
#pragma unroll
    for (int k = 0; k < 16; ++k) {
      float aw = attnW[w][h0 * 16 + k];
      unsigned vv = *(const unsigned*)(kvb + (size_t)gW[w][k] * 256 + 128 + c0);
      o0 += aw * bflo(vv);
      o1 += aw * bfhi(vv);
    }
    *(float2*)&o_out[(size_t)m * 128 + c0] = make_float2(o0, o1);
  }
}

// ---------------- K5: hidden = o@W_o + b_o; res = fres + hidden; LN; out = normed@W_out + b_out
__global__ __launch_bounds__(256) void final_fused(
    const float* __restrict__ o, const float* __restrict__ mrow,
    const float* __restrict__ W_o, const float* __restrict__ b_o,
    const float* __restrict__ ln_g, const float* __restrict__ ln_b,
    const float* __restrict__ W_out, const float* __restrict__ b_out,
    float* __restrict__ out) {
  __shared__ float oS[16 * 128];
  __shared__ float rS[16 * 128];
  __shared__ float redS[16][2][2];
  int t = threadIdx.x;
  int m0 = blockIdx.x * 16;
  for (int i = t; i < 2048; i += 256) oS[i] = o[(size_t)m0 * 128 + i];
  __syncthreads();
  int c = t & 127, half = t >> 7;
  float acc[8];
  {
    float bv = b_o[c];
#pragma unroll
    for (int j = 0; j < 8; ++j) acc[j] = bv;
  }
  for (int i = 0; i < 128; ++i) {
    float wv = W_o[i * 128 + c];
#pragma unroll
    for (int j = 0; j < 8; ++j) acc[j] += oS[(half * 8 + j) * 128 + i] * wv;
  }
#pragma unroll
  for (int j = 0; j < 8; ++j)
    acc[j] += mrow[(size_t)(m0 + half * 8 + j) * 256 + 128 + c];
  int wih = (t >> 6) & 1;
#pragma unroll
  for (int j = 0; j < 8; ++j) {
    float s1 = acc[j], s2 = acc[j] * acc[j];
#pragma unroll
    for (int off = 1; off < 64; off <<= 1) {
      s1 += __shfl_xor(s1, off);
      s2 += __shfl_xor(s2, off);
    }
    if ((t & 63) == 0) {
      redS[half * 8 + j][wih][0] = s1;
      redS[half * 8 + j][wih][1] = s2;
    }
  }
  __syncthreads();
  float gv = ln_g[c], lb = ln_b[c];
#pragma unroll
  for (int j = 0; j < 8; ++j) {
    int row = half * 8 + j;
    float s1 = redS[row][0][0] + redS[row][1][0];
    float s2 = redS[row][0][1] + redS[row][1][1];
    float mean = s1 * (1.0f / 128.0f);
    float var = s2 * (1.0f / 128.0f) - mean * mean;
    float rstd = rsqrtf(var + 1e-5f);
    rS[row * 128 + c] = (acc[j] - mean) * rstd * gv + lb;
  }
  __syncthreads();
  float acc2[8];
  {
    float b2 = b_out[c];
#pragma unroll
    for (int j = 0; j < 8; ++j) acc2[j] = b2;
  }
  for (int i = 0; i < 128; ++i) {
    float wv = W_out[i * 128 + c];
#pragma unroll
    for (int j = 0; j < 8; ++j) acc2[j] += rS[(half * 8 + j) * 128 + i] * wv;
  }
#pragma unroll
  for (int j = 0; j < 8; ++j)
    out[(size_t)(m0 + half * 8 + j) * 128 + c] = acc2[j];
}

extern "C" void kernel_launch(void* const* d_in, const int* in_sizes, int n_in,
                              void* d_out, int out_size, void* d_ws, size_t ws_size,
                              hipStream_t stream) {
  const float* feats    = (const float*)d_in[0];
  const int*   node_idx = (const int*)d_in[1];
  const int*   group_idx= (const int*)d_in[2];
  const float* ppfs     = (const float*)d_in[3];
  const float* W_a      = (const float*)d_in[4];
  const float* b_a      = (const float*)d_in[5];
  const float* W_in     = (const float*)d_in[6];
  const float* b_in     = (const float*)d_in[7];
  const float* W_q      = (const float*)d_in[8];
  const float* b_q      = (const float*)d_in[9];
  const float* W_k      = (const float*)d_in[10];
  const float* b_k      = (const float*)d_in[11];
  const float* W_v      = (const float*)d_in[12];
  const float* b_v      = (const float*)d_in[13];
  const float* W_p      = (const float*)d_in[14];
  // b_p (d_in[15]) unused: its score contribution is constant over k -> cancels in softmax.
  const float* W_o      = (const float*)d_in[16];
  const float* b_o      = (const float*)d_in[17];
  const float* ln_g     = (const float*)d_in[18];
  const float* ln_b     = (const float*)d_in[19];
  const float* W_out    = (const float*)d_in[20];
  const float* b_out    = (const float*)d_in[21];
  float* out = (float*)d_out;

  // ws layout (float units)
  float* ws   = (float*)d_ws;
  ushort* kvb = (ushort*)ws;              // 40000*256 bf16 -> 5,120,000 floats
  float* mrow = ws + 5120000;             // 20000*256 f32  -> 5,120,000
  ushort* qpb = (ushort*)(ws + 10240000); // 20000*512 bf16 -> 5,120,000 floats
  float* T    = ws + 15360000;            // 4096*128 f32   ->   524,288
  float* o    = ws + 15884288;            // 20000*128 f32  -> 2,560,000
  float* Wkv  = ws + 18444288;            // 64*256
  float* bkv  = ws + 18460672;            // 256
  float* Wbig = ws + 18460928;            // 64*768
  float* bbig = ws + 18510080;            // 768

  weight_prep1<<<3, 256, 0, stream>>>(W_in, b_in, W_q, b_q, W_k, b_k, W_v, b_v,
                                      Wkv, bkv, Wbig, bbig);
  weight_prep2<<<8, 256, 0, stream>>>(W_p, Wbig, bbig);
  mega_proj<<<5512, 256, 0, stream>>>(feats, node_idx, Wkv, bkv, Wbig, bbig,
                                      W_a, b_a, kvb, mrow, qpb, T);
  attn_fused<<<20000 / 4, 256, 0, stream>>>(kvb, mrow, qpb, T, ppfs, group_idx, o);
  final_fused<<<20000 / 16, 256, 0, stream>>>(o, mrow, W_o, b_o, ln_g, ln_b,
                                              W_out, b_out, out);
}

// Round 9
// 309.807 us; speedup vs baseline: 1.4182x; 1.0704x over previous
//
#include <hip/hip_runtime.h>

#define TQ 4096  // table resolution over x in [0,12]

__device__ __forceinline__ ushort f2bf(float x) {
  union { float f; unsigned u; } v; v.f = x;
  unsigned r = v.u + 0x7FFFu + ((v.u >> 16) & 1u);
  return (ushort)(r >> 16);
}
__device__ __forceinline__ float bflo(unsigned u) {
  union { unsigned u; float f; } v; v.u = u << 16;
  return v.f;
}
__device__ __forceinline__ float bfhi(unsigned u) {
  union { unsigned u; float f; } v; v.u = u & 0xffff0000u;
  return v.f;
}

// ---------------- W1: compose Wc{q,k,v} = W_in @ W_{q,k,v}; biases; copy W_in into Wbig[:,128:256]
// Wbig layout (64 x 768): [:,0:128]=Wcq  [:,128:256]=W_in  [:,256:768]=Wqp (filled by W2)
// Wkv  layout (64 x 256): [:,0:128]=Wck  [:,128:256]=Wcv
__global__ __launch_bounds__(256) void weight_prep1(
    const float* __restrict__ W_in, const float* __restrict__ b_in,
    const float* __restrict__ W_q, const float* __restrict__ b_q,
    const float* __restrict__ W_k, const float* __restrict__ b_k,
    const float* __restrict__ W_v, const float* __restrict__ b_v,
    float* __restrict__ Wkv, float* __restrict__ bkv,
    float* __restrict__ Wbig, float* __restrict__ bbig) {
  __shared__ float WinS[64 * 128];
  __shared__ float binS[128];
  int t = threadIdx.x;
  for (int i = t; i < 8192; i += 256) WinS[i] = W_in[i];
  if (t < 128) binS[t] = b_in[t];
  __syncthreads();
  const float* W; const float* b;
  int which = blockIdx.x;
  if (which == 0) { W = W_q; b = b_q; }
  else if (which == 1) { W = W_k; b = b_k; }
  else { W = W_v; b = b_v; }
  int c = t & 127, ih = t >> 7;  // ih selects rows ih*32 .. ih*32+31
  float acc[32] = {};
  float bacc = 0.f;
  for (int o = 0; o < 128; ++o) {
    float wv = W[o * 128 + c];
    bacc += binS[o] * wv;
#pragma unroll
    for (int j = 0; j < 32; ++j) acc[j] += WinS[(ih * 32 + j) * 128 + o] * wv;
  }
  bacc += b[c];
  if (which == 0) {
#pragma unroll
    for (int j = 0; j < 32; ++j) {
      int i = ih * 32 + j;
      Wbig[i * 768 + c] = acc[j];
      Wbig[i * 768 + 128 + c] = WinS[i * 128 + c];
    }
    if (ih == 0) { bbig[c] = bacc; bbig[128 + c] = binS[c]; }
  } else if (which == 1) {
#pragma unroll
    for (int j = 0; j < 32; ++j) Wkv[(ih * 32 + j) * 256 + c] = acc[j];
    if (ih == 0) bkv[c] = bacc;
  } else {
#pragma unroll
    for (int j = 0; j < 32; ++j) Wkv[(ih * 32 + j) * 256 + 128 + c] = acc[j];
    if (ih == 0) bkv[128 + c] = bacc;
  }
}

// ---------------- W2: Wqp[i][h*128+c] = sum_d Wcq[i][h*32+d] * W_p[c][h*32+d]  -> Wbig[:,256:768]
__global__ __launch_bounds__(256) void weight_prep2(
    const float* __restrict__ W_p, float* Wbig, float* bbig) {
  __shared__ float WcqS[64][33];
  __shared__ float bcqS[32];
  int t = threadIdx.x;
  int blk = blockIdx.x;     // 8 blocks, each 64 hc-columns
  int h = blk >> 1;
  for (int idx = t; idx < 2048; idx += 256) {
    int i = idx >> 5, d = idx & 31;
    WcqS[i][d] = Wbig[i * 768 + h * 32 + d];
  }
  if (t < 32) bcqS[t] = bbig[h * 32 + t];
  __syncthreads();
  int hc = blk * 64 + (t & 63);  // global col in [0,512)
  int c = hc & 127;
  int rg = t >> 6;               // 4 row-groups x 16 rows
  float acc[16] = {};
  float bacc = 0.f;
  for (int d = 0; d < 32; ++d) {
    float wp = W_p[c * 128 + h * 32 + d];
    bacc += bcqS[d] * wp;
#pragma unroll
    for (int j = 0; j < 16; ++j) acc[j] += WcqS[rg * 16 + j][d] * wp;
  }
#pragma unroll
  for (int j = 0; j < 16; ++j) Wbig[(rg * 16 + j) * 768 + 256 + hc] = acc[j];
  if (rg == 0) bbig[256 + hc] = bacc;
}

// ---------------- mega_proj: blocks [0,2500) proj_kv ; [2500,5000) proj_m ; [5000,5512) build_table
// proj_kv:     kvb[n][256] (bf16) = feats @ Wkv + bkv
// proj_m:      mrow[m][0:128]=q, [128:256]=fres (f32);  qpb[m][512] (bf16)
// build_table: Tq[q][cp] = float4{T[q][2cp],T[q][2cp+1],T[q+1][2cp],T[q+1][2cp+1]}
__global__ __launch_bounds__(256) void mega_proj(
    const float* __restrict__ feats, const int* __restrict__ node_idx,
    const float* __restrict__ Wkv, const float* __restrict__ bkv,
    const float* __restrict__ Wbig, const float* __restrict__ bbig,
    const float* __restrict__ W_a, const float* __restrict__ b_a,
    ushort* __restrict__ kvb, float* __restrict__ mrow,
    ushort* __restrict__ qpb, float4* __restrict__ Tq) {
  __shared__ float smem[64 * 20];
  int t = threadIdx.x;
  int b = blockIdx.x;
  if (b < 2500) {
    // ---- proj_kv: 16 rows
    float (*fTS)[20] = (float(*)[20])smem;
    int row0 = b * 16;
#pragma unroll
    for (int ii = 0; ii < 4; ++ii) {
      int idx = ii * 256 + t;
      int r = idx >> 6, i = idx & 63;
      fTS[i][r] = feats[(size_t)(row0 + r) * 64 + i];
    }
    __syncthreads();
    int c = t;
    float bv = bkv[c];
    float acc[16];
#pragma unroll
    for (int j = 0; j < 16; ++j) acc[j] = bv;
    for (int i = 0; i < 64; ++i) {
      float w = Wkv[i * 256 + c];
      float fv[16];
      *(float4*)&fv[0]  = *(const float4*)&fTS[i][0];
      *(float4*)&fv[4]  = *(const float4*)&fTS[i][4];
      *(float4*)&fv[8]  = *(const float4*)&fTS[i][8];
      *(float4*)&fv[12] = *(const float4*)&fTS[i][12];
#pragma unroll
      for (int j = 0; j < 16; ++j) acc[j] += fv[j] * w;
    }
#pragma unroll
    for (int j = 0; j < 16; ++j)
      kvb[(size_t)(row0 + j) * 256 + c] = f2bf(acc[j]);
  } else if (b < 5000) {
    // ---- proj_m: 8 m-rows
    float (*fTS)[12] = (float(*)[12])smem;
    int m0 = (b - 2500) * 8;
#pragma unroll
    for (int ii = 0; ii < 2; ++ii) {
      int idx = ii * 256 + t;
      int r = idx >> 6, i = idx & 63;
      int ni = node_idx[m0 + r];
      fTS[i][r] = feats[(size_t)ni * 64 + i];
    }
    __syncthreads();
    int c = t;  // composed cols {c, 256+c, 512+c} of Wbig
    float a0[8], a1[8], a2[8];
    float b0 = bbig[c], b1 = bbig[256 + c], b2 = bbig[512 + c];
#pragma unroll
    for (int j = 0; j < 8; ++j) { a0[j] = b0; a1[j] = b1; a2[j] = b2; }
    for (int i = 0; i < 64; ++i) {
      float w0 = Wbig[i * 768 + c];
      float w1 = Wbig[i * 768 + 256 + c];
      float w2 = Wbig[i * 768 + 512 + c];
      float fv[8];
      *(float4*)&fv[0] = *(const float4*)&fTS[i][0];
      *(float4*)&fv[4] = *(const float4*)&fTS[i][4];
#pragma unroll
      for (int j = 0; j < 8; ++j) {
        a0[j] += fv[j] * w0; a1[j] += fv[j] * w1; a2[j] += fv[j] * w2;
      }
    }
#pragma unroll
    for (int j = 0; j < 8; ++j) {
      int m = m0 + j;
      mrow[(size_t)m * 256 + c] = a0[j];            // q (c<128) | fres (c>=128)
      qpb[(size_t)m * 512 + c] = f2bf(a1[j]);       // qp col c
      qpb[(size_t)m * 512 + 256 + c] = f2bf(a2[j]); // qp col 256+c
    }
  } else {
    // ---- build_table: 8 Tq rows per block; needs 9 rows of sin/cos
    float (*sS)[64] = (float(*)[64])smem;
    float (*cS)[64] = (float(*)[64])(smem + 576);
    int row0 = (b - 5000) * 8;
    for (int i = t; i < 576; i += 256) {
      int r = i >> 6, j = i & 63;
      float x = (float)(row0 + r) * (12.0f / (float)(TQ - 1));
      float theta = expf(-(float)j * (9.210340371976184f / 64.0f));  // 10000^(-j/64)
      float om = x * theta;
      sS[r][j] = sinf(om);
      cS[r][j] = cosf(om);
    }
    __syncthreads();
    int cp = t & 63;      // channel pair: channels 2cp, 2cp+1
    int qr = t >> 6;      // row group: rows qr*2, qr*2+1 (+1 lookahead)
    int c0 = cp * 2, c1 = c0 + 1;
    float g0[3], g1[3];
    {
      float bb0 = b_a[c0], bb1 = b_a[c1];
#pragma unroll
      for (int r = 0; r < 3; ++r) { g0[r] = bb0; g1[r] = bb1; }
    }
    for (int j = 0; j < 64; ++j) {
      float ws0 = W_a[(2 * j) * 128 + c0];
      float wc0 = W_a[(2 * j + 1) * 128 + c0];
      float ws1 = W_a[(2 * j) * 128 + c1];
      float wc1 = W_a[(2 * j + 1) * 128 + c1];
#pragma unroll
      for (int r = 0; r < 3; ++r) {
        int rr = qr * 2 + r;
        float sv = sS[rr][j], cv = cS[rr][j];
        g0[r] += sv * ws0 + cv * wc0;
        g1[r] += sv * ws1 + cv * wc1;
      }
    }
#pragma unroll
    for (int r = 0; r < 2; ++r) {
      int row = row0 + qr * 2 + r;
      Tq[(size_t)row * 64 + cp] = make_float4(g0[r], g1[r], g0[r + 1], g1[r + 1]);
    }
  }
}

// ---------------- attn: one wave per m (4 m per block); NO barriers (all LDS wave-private)
__global__ __launch_bounds__(256) void attn_fused(
    const ushort* __restrict__ kvb, const float* __restrict__ mrow,
    const ushort* __restrict__ qpb, const float4* __restrict__ Tq,
    const float* __restrict__ ppfs, const int* __restrict__ group_idx,
    float* __restrict__ o_out) {
  __shared__ unsigned posW[4][8][68];   // packed bf16x2, one 8-k batch at a time
  __shared__ unsigned qpW[4][4][68];    // packed bf16x2
  __shared__ float qW[4][4][36];        // per-head q (f32)
  __shared__ float attnW[4][64];
  __shared__ float ppfW[4][64];
  __shared__ int gW[4][16];

  int t = threadIdx.x;
  int w = t >> 6;
  int lane = t & 63;
  int m = blockIdx.x * 4 + w;

  // ---- stage per-m data (all arrays are [w]-private: no __syncthreads needed anywhere)
  ppfW[w][lane] = ppfs[(size_t)m * 64 + lane];
  if (lane < 16) gW[w][lane] = group_idx[m * 16 + lane];
  const float* mr = mrow + (size_t)m * 256;
  {
    float q0 = mr[lane];
    float q1 = mr[64 + lane];
    qW[w][lane >> 5][lane & 31] = q0;
    int c1 = 64 + lane;
    qW[w][c1 >> 5][c1 & 31] = q1;
  }
  {
    uint4 qpu = ((const uint4*)(qpb + (size_t)m * 512))[lane];
    int j = lane * 4;         // uint index within row (0..255)
    int hh = j >> 6, j2 = j & 63;
    qpW[w][hh][j2 + 0] = qpu.x;
    qpW[w][hh][j2 + 1] = qpu.y;
    qpW[w][hh][j2 + 2] = qpu.z;
    qpW[w][hh][j2 + 3] = qpu.w;
  }

  int h = lane >> 4, k = lane & 15;
  int g = gW[w][k];

  // ---- qk dot (issue the gather early; overlaps with pos loop below)
  float s = 0.f;
  {
    const uint4* kp = (const uint4*)(kvb + (size_t)g * 256 + h * 32);  // 16B aligned
#pragma unroll
    for (int d8 = 0; d8 < 4; ++d8) {
      uint4 kk = kp[d8];
      float4 qv0 = *(const float4*)&qW[w][h][d8 * 8];
      float4 qv1 = *(const float4*)&qW[w][h][d8 * 8 + 4];
      s += qv0.x * bflo(kk.x) + qv0.y * bfhi(kk.x) +
           qv0.z * bflo(kk.y) + qv0.w * bfhi(kk.y) +
           qv1.x * bflo(kk.z) + qv1.y * bfhi(kk.z) +
           qv1.z * bflo(kk.w) + qv1.w * bfhi(kk.w);
    }
  }

  // ---- pos (lerp of paired-row table) + pos.qp dot, k in two batches of 8
  const float TS = (float)(TQ - 1) / 12.0f;
  for (int kb = 0; kb < 2; ++kb) {
#pragma unroll
    for (int k2 = 0; k2 < 8; ++k2) {
      int kk = kb * 8 + k2;
      float p0 = -1e30f, p1 = -1e30f;
#pragma unroll
      for (int a = 0; a < 4; ++a) {
        float x = ppfW[w][kk * 4 + a] * 3.8197186342054885f;  // FACTOR_A
        float u = x * TS;
        int i0 = min((int)u, TQ - 2);
        float fr = u - (float)i0;
        float4 tv = Tq[(size_t)i0 * 64 + lane];  // {T[i0][c0],T[i0][c0+1],T[i0+1][c0],T[i0+1][c0+1]}
        p0 = fmaxf(p0, tv.x + fr * (tv.z - tv.x));
        p1 = fmaxf(p1, tv.y + fr * (tv.w - tv.y));
      }
      posW[w][k2][lane] = (unsigned)f2bf(p0) | ((unsigned)f2bf(p1) << 16);
    }
    if ((k >> 3) == kb) {
      int k2 = k & 7;
#pragma unroll 8
      for (int c4 = 0; c4 < 32; ++c4) {
        unsigned pu0 = posW[w][k2][2 * c4], pu1 = posW[w][k2][2 * c4 + 1];
        unsigned qu0 = qpW[w][h][2 * c4], qu1 = qpW[w][h][2 * c4 + 1];
        s += bflo(pu0) * bflo(qu0) + bfhi(pu0) * bfhi(qu0) +
             bflo(pu1) * bflo(qu1) + bfhi(pu1) * bfhi(qu1);
      }
    }
  }

  // ---- softmax over k (width 16)
  {
    s *= 0.17677669529663687f;  // 1/sqrt(32); q.b_p term cancels in softmax
    float mx = s;
#pragma unroll
    for (int off = 1; off < 16; off <<= 1) mx = fmaxf(mx, __shfl_xor(mx, off));
    float e = __expf(s - mx);
    float sum = e;
#pragma unroll
    for (int off = 1; off < 16; off <<= 1) sum += __shfl_xor(sum, off);
    attnW[w][lane] = e / sum;
  }

  // ---- o[c] = sum_k attn[h(c)][k] * v[g_k][c]
  {
    int c0 = lane * 2;
    float o0 = 0.f, o1 = 0.f;
    int h0 = lane >> 4;  // head of channels c0, c0+1
#pragma unroll
    for (int kk = 0; kk < 16; ++kk) {
      float aw = attnW[w][h0 * 16 + kk];
      unsigned vv = *(const unsigned*)(kvb + (size_t)gW[w][kk] * 256 + 128 + c0);
      o0 += aw * bflo(vv);
      o1 += aw * bfhi(vv);
    }
    *(float2*)&o_out[(size_t)m * 128 + c0] = make_float2(o0, o1);
  }
}

// ---------------- K5: hidden = o@W_o + b_o; res = fres + hidden; LN; out = normed@W_out + b_out
__global__ __launch_bounds__(256) void final_fused(
    const float* __restrict__ o, const float* __restrict__ mrow,
    const float* __restrict__ W_o, const float* __restrict__ b_o,
    const float* __restrict__ ln_g, const float* __restrict__ ln_b,
    const float* __restrict__ W_out, const float* __restrict__ b_out,
    float* __restrict__ out) {
  __shared__ float oS[16 * 128];
  __shared__ float rS[16 * 128];
  __shared__ float redS[16][2][2];
  int t = threadIdx.x;
  int m0 = blockIdx.x * 16;
  for (int i = t; i < 2048; i += 256) oS[i] = o[(size_t)m0 * 128 + i];
  __syncthreads();
  int c = t & 127, half = t >> 7;
  float acc[8];
  {
    float bv = b_o[c];
#pragma unroll
    for (int j = 0; j < 8; ++j) acc[j] = bv;
  }
  for (int i = 0; i < 128; ++i) {
    float wv = W_o[i * 128 + c];
#pragma unroll
    for (int j = 0; j < 8; ++j) acc[j] += oS[(half * 8 + j) * 128 + i] * wv;
  }
#pragma unroll
  for (int j = 0; j < 8; ++j)
    acc[j] += mrow[(size_t)(m0 + half * 8 + j) * 256 + 128 + c];
  int wih = (t >> 6) & 1;
#pragma unroll
  for (int j = 0; j < 8; ++j) {
    float s1 = acc[j], s2 = acc[j] * acc[j];
#pragma unroll
    for (int off = 1; off < 64; off <<= 1) {
      s1 += __shfl_xor(s1, off);
      s2 += __shfl_xor(s2, off);
    }
    if ((t & 63) == 0) {
      redS[half * 8 + j][wih][0] = s1;
      redS[half * 8 + j][wih][1] = s2;
    }
  }
  __syncthreads();
  float gv = ln_g[c], lb = ln_b[c];
#pragma unroll
  for (int j = 0; j < 8; ++j) {
    int row = half * 8 + j;
    float s1 = redS[row][0][0] + redS[row][1][0];
    float s2 = redS[row][0][1] + redS[row][1][1];
    float mean = s1 * (1.0f / 128.0f);
    float var = s2 * (1.0f / 128.0f) - mean * mean;
    float rstd = rsqrtf(var + 1e-5f);
    rS[row * 128 + c] = (acc[j] - mean) * rstd * gv + lb;
  }
  __syncthreads();
  float acc2[8];
  {
    float b2 = b_out[c];
#pragma unroll
    for (int j = 0; j < 8; ++j) acc2[j] = b2;
  }
  for (int i = 0; i < 128; ++i) {
    float wv = W_out[i * 128 + c];
#pragma unroll
    for (int j = 0; j < 8; ++j) acc2[j] += rS[(half * 8 + j) * 128 + i] * wv;
  }
#pragma unroll
  for (int j = 0; j < 8; ++j)
    out[(size_t)(m0 + half * 8 + j) * 128 + c] = acc2[j];
}

extern "C" void kernel_launch(void* const* d_in, const int* in_sizes, int n_in,
                              void* d_out, int out_size, void* d_ws, size_t ws_size,
                              hipStream_t stream) {
  const float* feats    = (const float*)d_in[0];
  const int*   node_idx = (const int*)d_in[1];
  const int*   group_idx= (const int*)d_in[2];
  const float* ppfs     = (const float*)d_in[3];
  const float* W_a      = (const float*)d_in[4];
  const float* b_a      = (const float*)d_in[5];
  const float* W_in     = (const float*)d_in[6];
  const float* b_in     = (const float*)d_in[7];
  const float* W_q      = (const float*)d_in[8];
  const float* b_q      = (const float*)d_in[9];
  const float* W_k      = (const float*)d_in[10];
  const float* b_k      = (const float*)d_in[11];
  const float* W_v      = (const float*)d_in[12];
  const float* b_v      = (const float*)d_in[13];
  const float* W_p      = (const float*)d_in[14];
  // b_p (d_in[15]) unused: its score contribution is constant over k -> cancels in softmax.
  const float* W_o      = (const float*)d_in[16];
  const float* b_o      = (const float*)d_in[17];
  const float* ln_g     = (const float*)d_in[18];
  const float* ln_b     = (const float*)d_in[19];
  const float* W_out    = (const float*)d_in[20];
  const float* b_out    = (const float*)d_in[21];
  float* out = (float*)d_out;

  // ws layout (float units)
  float* ws   = (float*)d_ws;
  ushort* kvb = (ushort*)ws;              // 40000*256 bf16 -> 5,120,000 floats
  float* mrow = ws + 5120000;             // 20000*256 f32  -> 5,120,000
  ushort* qpb = (ushort*)(ws + 10240000); // 20000*512 bf16 -> 5,120,000 floats
  float4* Tq  = (float4*)(ws + 15360000); // 4096*64 float4 -> 1,048,576 floats (16B-aligned offset)
  float* o    = ws + 16408576;            // 20000*128 f32  -> 2,560,000
  float* Wkv  = ws + 18968576;            // 64*256
  float* bkv  = ws + 18984960;            // 256
  float* Wbig = ws + 18985216;            // 64*768
  float* bbig = ws + 19034368;            // 768

  weight_prep1<<<3, 256, 0, stream>>>(W_in, b_in, W_q, b_q, W_k, b_k, W_v, b_v,
                                      Wkv, bkv, Wbig, bbig);
  weight_prep2<<<8, 256, 0, stream>>>(W_p, Wbig, bbig);
  mega_proj<<<5512, 256, 0, stream>>>(feats, node_idx, Wkv, bkv, Wbig, bbig,
                                      W_a, b_a, kvb, mrow, qpb, Tq);
  attn_fused<<<20000 / 4, 256, 0, stream>>>(kvb, mrow, qpb, Tq, ppfs, group_idx, o);
  final_fused<<<20000 / 16, 256, 0, stream>>>(o, mrow, W_o, b_o, ln_g, ln_b,
                                              W_out, b_out, out);
}